// Round 9
// baseline (129.524 us; speedup 1.0000x reference)
//
#include <hip/hip_runtime.h>
#include <math.h>

// Problem constants (fixed by reference setup_inputs)
constexpr int B   = 128;
constexpr int T   = 300;
constexpr int D   = 1024;   // video dim
constexpr int DA  = 128;    // audio dim
constexpr int TS  = T - 1;  // 299 similarities per batch
constexpr int K   = 32;
constexpr int KP1 = K + 1;

constexpr int SEGW    = 19;    // sims per wave (16 waves/batch: 16*19=304>=299)
constexpr int SIMS_LD = 320;   // padded stride (floats): 1280 B = 10 cache lines,
                               // so no 128B line is shared between batches
#define EPS_D 1e-5

__device__ __forceinline__ void loadrow(const float* __restrict__ row, int lane, float r[16]) {
    const float4* f = (const float4*)row;
#pragma unroll
    for (int j = 0; j < 4; ++j) {
        float4 x = f[lane + 64 * j];
        r[4 * j + 0] = x.x; r[4 * j + 1] = x.y;
        r[4 * j + 2] = x.z; r[4 * j + 3] = x.w;
    }
}

// Single-dispatch producer/consumer:
//   512 blocks x 256 thr; block = (batch b, quarter q). 4 waves compute
//   4x19 sims (f64 accumulation — absmax 0.0 in R0/R1/R4/R6) into padded
//   global sims. Last finishing block of each batch (device-scope atomic
//   counter) becomes the consumer: LDS rank-select + gather. No grid.sync,
//   no spin — blocks that aren't last simply exit.
__global__ __launch_bounds__(256) void fusedpc_kernel(const float* __restrict__ video,
                                                      const float* __restrict__ audio,
                                                      float* sims, int* cnt,
                                                      float* __restrict__ out) {
    int b   = blockIdx.x >> 2;
    int q   = blockIdx.x & 3;
    int tid = threadIdx.x;
    int w   = tid >> 6;
    int lane = tid & 63;

    const float* vb = video + (size_t)b * T * D;

    // ---- producer: sims for segment g = q*4+w, s in [s0, s0+19) ----
    {
        int g  = (q << 2) | w;          // 0..15
        int s0 = g * SEGW;

        float p[16];
        loadrow(vb + (size_t)min(s0, TS) * D, lane, p);
        double pn0 = 0.0;
#pragma unroll
        for (int j = 0; j < 16; ++j) pn0 += (double)p[j] * (double)p[j];

        double cnA[SEGW], dtA[SEGW];
#pragma unroll
        for (int i = 0; i < SEGW; ++i) {
            int s = s0 + i;
            int rowIdx = min(s + 1, TS);   // clamp tail loads
            float c[16];
            loadrow(vb + (size_t)rowIdx * D, lane, c);
            double cn = 0.0, dt = 0.0;
#pragma unroll
            for (int j = 0; j < 16; ++j) {
                cn += (double)c[j] * (double)c[j];
                dt += (double)c[j] * (double)p[j];
            }
            cnA[i] = cn; dtA[i] = dt;
#pragma unroll
            for (int j = 0; j < 16; ++j) p[j] = c[j];
        }
#pragma unroll
        for (int o = 32; o; o >>= 1) {
            pn0 += __shfl_xor(pn0, o);
#pragma unroll
            for (int i = 0; i < SEGW; ++i) {
                cnA[i] += __shfl_xor(cnA[i], o);
                dtA[i] += __shfl_xor(dtA[i], o);
            }
        }
        if (lane == 0) {
            double nprev = sqrt(pn0) + EPS_D;
#pragma unroll
            for (int i = 0; i < SEGW; ++i) {
                int s = s0 + i;
                double ncur = sqrt(cnA[i]) + EPS_D;
                if (s < TS) sims[b * SIMS_LD + s] = (float)(fabs(dtA[i]) / (nprev * ncur));
                nprev = ncur;
            }
        }
    }

    // ---- handoff: release writes, count quarters; last block consumes ----
    __threadfence();                       // make this thread's sims writes device-visible
    __syncthreads();
    __shared__ int isLast;
    if (tid == 0) {
        int old = atomicAdd(&cnt[b], 1);   // device-scope
        isLast = (old == 3);
    }
    __syncthreads();
    if (!isLast) return;
    __threadfence();                       // acquire: reads below ordered after atomic

    // ---- consumer: rank-select in LDS ----
    __shared__ float S[TS];
    __shared__ int   idxs[KP1];
    for (int e = tid; e < TS; e += 256) S[e] = sims[b * SIMS_LD + e];
    if (tid == 0) idxs[0] = 0;
    __syncthreads();

    for (int e = tid; e < TS; e += 256) {
        float val = S[e];
        int rank = 0;
#pragma unroll 4
        for (int j = 0; j < TS; ++j) {
            float sj = S[j];
            rank += (sj < val) || (sj == val && j < e);
        }
        if (rank < K) idxs[rank + 1] = e + 1;   // ranks unique => no conflicts
    }
    __syncthreads();

    // ---- consumer: gather 33 video + audio rows ----
#pragma unroll 4
    for (int k = 0; k < KP1; ++k) {
        int t = idxs[k];
        const float4* vs = (const float4*)(vb + (size_t)t * D);
        float4*       vd = (float4*)(out + ((size_t)b * KP1 + k) * D);
        vd[tid] = vs[tid];                  // 256 float4 = full row
    }
    const float* ab   = audio + (size_t)b * T * DA;
    float*       outA = out + (size_t)B * KP1 * D + (size_t)b * KP1 * DA;
    for (int a = tid; a < KP1 * (DA / 4); a += 256) {
        int k = a >> 5, off = a & 31;
        int t = idxs[k];
        ((float4*)(outA + (size_t)k * DA))[off] =
            ((const float4*)(ab + (size_t)t * DA))[off];
    }
}

extern "C" void kernel_launch(void* const* d_in, const int* in_sizes, int n_in,
                              void* d_out, int out_size, void* d_ws, size_t ws_size,
                              hipStream_t stream) {
    const float* video = (const float*)d_in[0];
    const float* audio = (const float*)d_in[1];
    float* out  = (float*)d_out;

    float* sims = (float*)d_ws;                                  // 128*320*4 = 160 KB
    int*   cnt  = (int*)((char*)d_ws + (size_t)B * SIMS_LD * sizeof(float));

    // zero the per-batch quarter counters (capture-safe async memset)
    hipMemsetAsync(cnt, 0, B * sizeof(int), stream);

    fusedpc_kernel<<<B * 4, 256, 0, stream>>>(video, audio, sims, cnt, out);
}